// Round 1
// baseline (6598.273 us; speedup 1.0000x reference)
//
#include <hip/hip_runtime.h>

// ---------------------------------------------------------------------------
// GraphSAGE 2-layer hetero (R=2) + edge dot-product scorer.
// Correctness-first baseline:
//   1. scatter-add x[src] -> acc[r][dst], degree count (scalar f32 atomics)
//   2. mean = acc / max(deg,1)
//   3. layer GEMM: out = [relu]( x@ (Ws0+Ws1) + m0@Wn0 + m1@Wn1 + b0+b1 )
//   4. repeat for layer 2 (Fout=64)
//   5. pos/neg edge dot products -> d_out[0:E), d_out[E:E+En)
// ---------------------------------------------------------------------------

__global__ void scatter_kernel(const float* __restrict__ feat, // [N,F]
                               const int* __restrict__ edges,  // [R,2,E]
                               float* __restrict__ acc,        // [R,N,F]
                               float* __restrict__ deg,        // [R,N]
                               int N, int F, int E, int R)
{
    long long tid = (long long)blockIdx.x * blockDim.x + threadIdx.x;
    int chunks = F >> 2;                       // float4 chunks per row
    long long total = (long long)R * E * chunks;
    if (tid >= total) return;
    int c = (int)(tid % chunks);
    long long re = tid / chunks;
    int e = (int)(re % E);
    int r = (int)(re / E);

    int src = edges[(size_t)r * 2 * E + e];
    int dst = edges[(size_t)r * 2 * E + E + e];

    float4 v = *(const float4*)(feat + (size_t)src * F + c * 4);
    float* a = acc + (size_t)r * N * F + (size_t)dst * F + (size_t)c * 4;
    atomicAdd(a + 0, v.x);
    atomicAdd(a + 1, v.y);
    atomicAdd(a + 2, v.z);
    atomicAdd(a + 3, v.w);
    if (c == 0) atomicAdd(deg + (size_t)r * N + dst, 1.0f);
}

__global__ void mean_kernel(float* __restrict__ acc,       // [R,N,F] in-place
                            const float* __restrict__ deg, // [R,N]
                            int N, int F, int R)
{
    long long tid = (long long)blockIdx.x * blockDim.x + threadIdx.x;
    int chunks = F >> 2;
    long long total = (long long)R * N * chunks;
    if (tid >= total) return;
    int c = (int)(tid % chunks);
    long long ri = tid / chunks;
    int i = (int)(ri % N);
    int r = (int)(ri / N);

    float d = deg[(size_t)r * N + i];
    float inv = 1.0f / fmaxf(d, 1.0f);
    float4* p = (float4*)(acc + (size_t)r * N * F + (size_t)i * F + (size_t)c * 4);
    float4 v = *p;
    v.x *= inv; v.y *= inv; v.z *= inv; v.w *= inv;
    *p = v;
}

// One block per node row; one thread per output column (Fout <= blockDim).
__global__ void layer_kernel(const float* __restrict__ xin,   // [N,Fin]
                             const float* __restrict__ mean,  // [2,N,Fin]
                             const float* __restrict__ Wself, // [2,Fin,Fout]
                             const float* __restrict__ Wn,    // [2,Fin,Fout]
                             const float* __restrict__ b,     // [2,Fout]
                             float* __restrict__ out,         // [N,Fout]
                             int N, int Fin, int Fout, int do_relu)
{
    int i = blockIdx.x;
    int j = threadIdx.x;
    extern __shared__ float sm[];          // 3*Fin floats
    float* xs = sm;
    float* m0 = sm + Fin;
    float* m1 = sm + 2 * Fin;
    for (int k = threadIdx.x; k < Fin; k += blockDim.x) {
        xs[k] = xin[(size_t)i * Fin + k];
        m0[k] = mean[(size_t)i * Fin + k];
        m1[k] = mean[(size_t)N * Fin + (size_t)i * Fin + k];
    }
    __syncthreads();
    if (j >= Fout) return;

    float acc = b[j] + b[Fout + j];
    const size_t wstride = (size_t)Fin * Fout;
    for (int k = 0; k < Fin; ++k) {
        float ws = Wself[(size_t)k * Fout + j] + Wself[wstride + (size_t)k * Fout + j];
        acc = fmaf(xs[k], ws, acc);
        acc = fmaf(m0[k], Wn[(size_t)k * Fout + j], acc);
        acc = fmaf(m1[k], Wn[wstride + (size_t)k * Fout + j], acc);
    }
    if (do_relu) acc = fmaxf(acc, 0.0f);
    out[(size_t)i * Fout + j] = acc;
}

__global__ void score_kernel(const float* __restrict__ h, // [N,O]
                             const int* __restrict__ src,
                             const int* __restrict__ dst,
                             float* __restrict__ out, int E, int O)
{
    int e = blockIdx.x * blockDim.x + threadIdx.x;
    if (e >= E) return;
    const float* a = h + (size_t)src[e] * O;
    const float* c = h + (size_t)dst[e] * O;
    float s = 0.0f;
    for (int k = 0; k < O; k += 4) {
        float4 va = *(const float4*)(a + k);
        float4 vb = *(const float4*)(c + k);
        s = fmaf(va.x, vb.x, s);
        s = fmaf(va.y, vb.y, s);
        s = fmaf(va.z, vb.z, s);
        s = fmaf(va.w, vb.w, s);
    }
    out[e] = s;
}

extern "C" void kernel_launch(void* const* d_in, const int* in_sizes, int n_in,
                              void* d_out, int out_size, void* d_ws, size_t ws_size,
                              hipStream_t stream)
{
    const float* x     = (const float*)d_in[0];
    const int*   edges = (const int*)d_in[1];
    const int*   neg   = (const int*)d_in[2];
    const float* Wn1   = (const float*)d_in[3];
    const float* Ws1   = (const float*)d_in[4];
    const float* b1    = (const float*)d_in[5];
    const float* Wn2   = (const float*)d_in[6];
    const float* Ws2   = (const float*)d_in[7];
    const float* b2    = (const float*)d_in[8];
    float* out = (float*)d_out;

    const int Fin = 128, H = 128, O = 64, R = 2;
    const int N  = in_sizes[0] / Fin;        // 50000
    const int E  = in_sizes[1] / (R * 2);    // 800000
    const int En = in_sizes[2] / 2;          // 800000

    float* ws  = (float*)d_ws;
    float* acc = ws;                                   // [R, N, 128]
    float* deg = acc + (size_t)R * N * 128;            // [R, N]
    float* h1  = deg + (size_t)R * N;                  // [N, 128]
    float* h2  = h1 + (size_t)N * 128;                 // [N, 64]

    const size_t zero_bytes = ((size_t)R * N * 128 + (size_t)R * N) * sizeof(float);

    const int BS = 256;

    // ---- Layer 1 ----
    hipMemsetAsync(acc, 0, zero_bytes, stream);
    {
        long long total = (long long)R * E * (Fin / 4);
        long long nb = (total + BS - 1) / BS;
        scatter_kernel<<<(dim3)(unsigned)nb, BS, 0, stream>>>(x, edges, acc, deg, N, Fin, E, R);
    }
    {
        long long total = (long long)R * N * (Fin / 4);
        long long nb = (total + BS - 1) / BS;
        mean_kernel<<<(dim3)(unsigned)nb, BS, 0, stream>>>(acc, deg, N, Fin, R);
    }
    layer_kernel<<<N, 128, 3 * 128 * sizeof(float), stream>>>(
        x, acc, Ws1, Wn1, b1, h1, N, Fin, H, 1);

    // ---- Layer 2 ----
    hipMemsetAsync(acc, 0, zero_bytes, stream);
    {
        long long total = (long long)R * E * (H / 4);
        long long nb = (total + BS - 1) / BS;
        scatter_kernel<<<(dim3)(unsigned)nb, BS, 0, stream>>>(h1, edges, acc, deg, N, H, E, R);
    }
    {
        long long total = (long long)R * N * (H / 4);
        long long nb = (total + BS - 1) / BS;
        mean_kernel<<<(dim3)(unsigned)nb, BS, 0, stream>>>(acc, deg, N, H, R);
    }
    layer_kernel<<<N, 64, 3 * 128 * sizeof(float), stream>>>(
        h1, acc, Ws2, Wn2, b2, h2, N, H, O, 0);

    // ---- Scores ----
    // pos: relation 0 edges. src = edges[0,0,:], dst = edges[0,1,:]
    score_kernel<<<(E + BS - 1) / BS, BS, 0, stream>>>(h2, edges, edges + E, out, E, O);
    // neg: neg_edges[0,:], neg_edges[1,:]
    score_kernel<<<(En + BS - 1) / BS, BS, 0, stream>>>(h2, neg, neg + En, out + E, En, O);
}

// Round 2
// 1430.718 us; speedup vs baseline: 4.6119x; 4.6119x over previous
//
#include <hip/hip_runtime.h>

// ---------------------------------------------------------------------------
// GraphSAGE 2-layer hetero (R=2) + edge dot-product scorer.
// Round 2: replace float-atomic scatter with CSR build (counting sort by dst,
// done once per call since both layers share the edge list) + gather-based
// mean aggregation (one wave per (relation,node), coalesced row gathers,
// zero float atomics).
// ---------------------------------------------------------------------------

__global__ void hist_kernel(const int* __restrict__ edges, // [R,2,E]
                            int* __restrict__ cnt,         // [R,N]
                            int N, int E, int R)
{
    long long t = (long long)blockIdx.x * blockDim.x + threadIdx.x;
    long long total = (long long)R * E;
    if (t >= total) return;
    int e = (int)(t % E);
    int r = (int)(t / E);
    int dst = edges[(size_t)r * 2 * E + E + e];
    atomicAdd(&cnt[(size_t)r * N + dst], 1);
}

// One block (1024 threads) per relation: exclusive scan of cnt -> off.
__global__ void scan_kernel(const int* __restrict__ cnt, // [R,N]
                            int* __restrict__ off,       // [R,N]
                            int N)
{
    const int r = blockIdx.x;
    __shared__ int sm[1024];
    __shared__ int carry;
    if (threadIdx.x == 0) carry = 0;
    __syncthreads();
    for (int base = 0; base < N; base += 1024) {
        int i = base + threadIdx.x;
        int v = (i < N) ? cnt[(size_t)r * N + i] : 0;
        sm[threadIdx.x] = v;
        __syncthreads();
        // Hillis-Steele inclusive scan in LDS
        for (int s = 1; s < 1024; s <<= 1) {
            int t = (threadIdx.x >= s) ? sm[threadIdx.x - s] : 0;
            __syncthreads();
            sm[threadIdx.x] += t;
            __syncthreads();
        }
        if (i < N) off[(size_t)r * N + i] = carry + sm[threadIdx.x] - v;
        __syncthreads();
        if (threadIdx.x == 1023) carry += sm[1023];
        __syncthreads();
    }
}

__global__ void reorder_kernel(const int* __restrict__ edges, // [R,2,E]
                               const int* __restrict__ off,   // [R,N]
                               int* __restrict__ cursor,      // [R,N]
                               int* __restrict__ csr,         // [R,E] src ids
                               int N, int E, int R)
{
    long long t = (long long)blockIdx.x * blockDim.x + threadIdx.x;
    long long total = (long long)R * E;
    if (t >= total) return;
    int e = (int)(t % E);
    int r = (int)(t / E);
    int src = edges[(size_t)r * 2 * E + e];
    int dst = edges[(size_t)r * 2 * E + E + e];
    int pos = atomicAdd(&cursor[(size_t)r * N + dst], 1);
    csr[(size_t)r * E + off[(size_t)r * N + dst] + pos] = src;
}

// One wave per (relation, node): gather-sum src rows, divide by degree.
// F == 128: lane handles columns [2*lane, 2*lane+1] as float2.
__global__ __launch_bounds__(256) void
gather_mean_kernel(const float* __restrict__ feat, // [N,F]
                   const int* __restrict__ csr,    // [R,E]
                   const int* __restrict__ off,    // [R,N]
                   float* __restrict__ acc,        // [R,N,F]
                   int N, int F, int E)
{
    int w = (int)(((long long)blockIdx.x * blockDim.x + threadIdx.x) >> 6);
    int lane = threadIdx.x & 63;
    if (w >= 2 * N) return;
    int r = (w >= N) ? 1 : 0;
    int i = w - r * N;

    int o0 = off[(size_t)r * N + i];
    int o1 = (i + 1 < N) ? off[(size_t)r * N + i + 1] : E;
    int d = o1 - o0;
    const int* es = csr + (size_t)r * E;
    const int col = lane * 2;

    float sx = 0.0f, sy = 0.0f;
    int j = o0;
    for (; j + 3 < o1; j += 4) {
        int s0 = es[j], s1 = es[j + 1], s2 = es[j + 2], s3 = es[j + 3];
        float2 a = *(const float2*)(feat + (size_t)s0 * F + col);
        float2 b = *(const float2*)(feat + (size_t)s1 * F + col);
        float2 c = *(const float2*)(feat + (size_t)s2 * F + col);
        float2 e4 = *(const float2*)(feat + (size_t)s3 * F + col);
        sx += (a.x + b.x) + (c.x + e4.x);
        sy += (a.y + b.y) + (c.y + e4.y);
    }
    for (; j < o1; ++j) {
        int s0 = es[j];
        float2 a = *(const float2*)(feat + (size_t)s0 * F + col);
        sx += a.x; sy += a.y;
    }
    float inv = 1.0f / fmaxf((float)d, 1.0f);
    float2 res; res.x = sx * inv; res.y = sy * inv;
    *(float2*)(acc + (size_t)r * N * F + (size_t)i * F + col) = res;
}

// One block per node row; one thread per output column (Fout <= blockDim).
__global__ void layer_kernel(const float* __restrict__ xin,   // [N,Fin]
                             const float* __restrict__ mean,  // [2,N,Fin]
                             const float* __restrict__ Wself, // [2,Fin,Fout]
                             const float* __restrict__ Wn,    // [2,Fin,Fout]
                             const float* __restrict__ b,     // [2,Fout]
                             float* __restrict__ out,         // [N,Fout]
                             int N, int Fin, int Fout, int do_relu)
{
    int i = blockIdx.x;
    int j = threadIdx.x;
    extern __shared__ float sm[];          // 3*Fin floats
    float* xs = sm;
    float* m0 = sm + Fin;
    float* m1 = sm + 2 * Fin;
    for (int k = threadIdx.x; k < Fin; k += blockDim.x) {
        xs[k] = xin[(size_t)i * Fin + k];
        m0[k] = mean[(size_t)i * Fin + k];
        m1[k] = mean[(size_t)N * Fin + (size_t)i * Fin + k];
    }
    __syncthreads();
    if (j >= Fout) return;

    float acc = b[j] + b[Fout + j];
    const size_t wstride = (size_t)Fin * Fout;
    for (int k = 0; k < Fin; ++k) {
        float ws = Wself[(size_t)k * Fout + j] + Wself[wstride + (size_t)k * Fout + j];
        acc = fmaf(xs[k], ws, acc);
        acc = fmaf(m0[k], Wn[(size_t)k * Fout + j], acc);
        acc = fmaf(m1[k], Wn[wstride + (size_t)k * Fout + j], acc);
    }
    if (do_relu) acc = fmaxf(acc, 0.0f);
    out[(size_t)i * Fout + j] = acc;
}

__global__ void score_kernel(const float* __restrict__ h, // [N,O]
                             const int* __restrict__ src,
                             const int* __restrict__ dst,
                             float* __restrict__ out, int E, int O)
{
    int e = blockIdx.x * blockDim.x + threadIdx.x;
    if (e >= E) return;
    const float* a = h + (size_t)src[e] * O;
    const float* c = h + (size_t)dst[e] * O;
    float s = 0.0f;
    for (int k = 0; k < O; k += 4) {
        float4 va = *(const float4*)(a + k);
        float4 vb = *(const float4*)(c + k);
        s = fmaf(va.x, vb.x, s);
        s = fmaf(va.y, vb.y, s);
        s = fmaf(va.z, vb.z, s);
        s = fmaf(va.w, vb.w, s);
    }
    out[e] = s;
}

extern "C" void kernel_launch(void* const* d_in, const int* in_sizes, int n_in,
                              void* d_out, int out_size, void* d_ws, size_t ws_size,
                              hipStream_t stream)
{
    const float* x     = (const float*)d_in[0];
    const int*   edges = (const int*)d_in[1];
    const int*   neg   = (const int*)d_in[2];
    const float* Wn1   = (const float*)d_in[3];
    const float* Ws1   = (const float*)d_in[4];
    const float* b1    = (const float*)d_in[5];
    const float* Wn2   = (const float*)d_in[6];
    const float* Ws2   = (const float*)d_in[7];
    const float* b2    = (const float*)d_in[8];
    float* out = (float*)d_out;

    const int Fin = 128, H = 128, O = 64, R = 2;
    const int N  = in_sizes[0] / Fin;        // 50000
    const int E  = in_sizes[1] / (R * 2);    // 800000
    const int En = in_sizes[2] / 2;          // 800000

    float* ws  = (float*)d_ws;
    float* acc = ws;                                   // [R, N, 128]  51.2 MB
    float* h1  = acc + (size_t)R * N * 128;            // [N, 128]     25.6 MB
    float* h2  = h1 + (size_t)N * 128;                 // [N, 64]      12.8 MB
    int*   icnt   = (int*)(h2 + (size_t)N * 64);       // [R, N]
    int*   icur   = icnt + (size_t)R * N;              // [R, N]
    int*   ioff   = icur + (size_t)R * N;              // [R, N]
    int*   icsr   = ioff + (size_t)R * N;              // [R, E]

    const int BS = 256;

    // ---- CSR build (edges shared by both layers) ----
    hipMemsetAsync(icnt, 0, (size_t)2 * R * N * sizeof(int), stream);  // cnt+cursor
    {
        long long total = (long long)R * E;
        long long nb = (total + BS - 1) / BS;
        hist_kernel<<<(dim3)(unsigned)nb, BS, 0, stream>>>(edges, icnt, N, E, R);
    }
    scan_kernel<<<R, 1024, 0, stream>>>(icnt, ioff, N);
    {
        long long total = (long long)R * E;
        long long nb = (total + BS - 1) / BS;
        reorder_kernel<<<(dim3)(unsigned)nb, BS, 0, stream>>>(edges, ioff, icur, icsr, N, E, R);
    }

    const int gm_blocks = (2 * N * 64 + BS - 1) / BS;  // one wave per (r,node)

    // ---- Layer 1 ----
    gather_mean_kernel<<<gm_blocks, BS, 0, stream>>>(x, icsr, ioff, acc, N, Fin, E);
    layer_kernel<<<N, 128, 3 * 128 * sizeof(float), stream>>>(
        x, acc, Ws1, Wn1, b1, h1, N, Fin, H, 1);

    // ---- Layer 2 ----
    gather_mean_kernel<<<gm_blocks, BS, 0, stream>>>(h1, icsr, ioff, acc, N, H, E);
    layer_kernel<<<N, 64, 3 * 128 * sizeof(float), stream>>>(
        h1, acc, Ws2, Wn2, b2, h2, N, H, O, 0);

    // ---- Scores ----
    score_kernel<<<(E + BS - 1) / BS, BS, 0, stream>>>(h2, edges, edges + E, out, E, O);
    score_kernel<<<(En + BS - 1) / BS, BS, 0, stream>>>(h2, neg, neg + En, out + E, En, O);
}

// Round 3
// 984.119 us; speedup vs baseline: 6.7048x; 1.4538x over previous
//
#include <hip/hip_runtime.h>

// ---------------------------------------------------------------------------
// GraphSAGE 2-layer hetero (R=2) + edge dot-product scorer.
// Round 3: register-tiled f32 GEMM for the layer transform.
//   out[BMxBN] per block, 256 threads, 8x4 register tile per thread,
//   K=384 as three 128-chunks (x@Wc, m0@Wn0, m1@Wn1), LDS-staged BK=32.
//   Wself/bias pre-combined across the 2 relations by prep_kernel.
// CSR build + gather_mean + score unchanged from round 2.
// ---------------------------------------------------------------------------

__global__ void hist_kernel(const int* __restrict__ edges, // [R,2,E]
                            int* __restrict__ cnt,         // [R,N]
                            int N, int E, int R)
{
    long long t = (long long)blockIdx.x * blockDim.x + threadIdx.x;
    long long total = (long long)R * E;
    if (t >= total) return;
    int e = (int)(t % E);
    int r = (int)(t / E);
    int dst = edges[(size_t)r * 2 * E + E + e];
    atomicAdd(&cnt[(size_t)r * N + dst], 1);
}

// One block (1024 threads) per relation: exclusive scan of cnt -> off.
__global__ void scan_kernel(const int* __restrict__ cnt, // [R,N]
                            int* __restrict__ off,       // [R,N]
                            int N)
{
    const int r = blockIdx.x;
    __shared__ int sm[1024];
    __shared__ int carry;
    if (threadIdx.x == 0) carry = 0;
    __syncthreads();
    for (int base = 0; base < N; base += 1024) {
        int i = base + threadIdx.x;
        int v = (i < N) ? cnt[(size_t)r * N + i] : 0;
        sm[threadIdx.x] = v;
        __syncthreads();
        for (int s = 1; s < 1024; s <<= 1) {
            int t = (threadIdx.x >= s) ? sm[threadIdx.x - s] : 0;
            __syncthreads();
            sm[threadIdx.x] += t;
            __syncthreads();
        }
        if (i < N) off[(size_t)r * N + i] = carry + sm[threadIdx.x] - v;
        __syncthreads();
        if (threadIdx.x == 1023) carry += sm[1023];
        __syncthreads();
    }
}

__global__ void reorder_kernel(const int* __restrict__ edges, // [R,2,E]
                               const int* __restrict__ off,   // [R,N]
                               int* __restrict__ cursor,      // [R,N]
                               int* __restrict__ csr,         // [R,E] src ids
                               int N, int E, int R)
{
    long long t = (long long)blockIdx.x * blockDim.x + threadIdx.x;
    long long total = (long long)R * E;
    if (t >= total) return;
    int e = (int)(t % E);
    int r = (int)(t / E);
    int src = edges[(size_t)r * 2 * E + e];
    int dst = edges[(size_t)r * 2 * E + E + e];
    int pos = atomicAdd(&cursor[(size_t)r * N + dst], 1);
    csr[(size_t)r * E + off[(size_t)r * N + dst] + pos] = src;
}

// One wave per (relation, node): gather-sum src rows, divide by degree.
__global__ __launch_bounds__(256) void
gather_mean_kernel(const float* __restrict__ feat, // [N,F]
                   const int* __restrict__ csr,    // [R,E]
                   const int* __restrict__ off,    // [R,N]
                   float* __restrict__ acc,        // [R,N,F]
                   int N, int F, int E)
{
    int w = (int)(((long long)blockIdx.x * blockDim.x + threadIdx.x) >> 6);
    int lane = threadIdx.x & 63;
    if (w >= 2 * N) return;
    int r = (w >= N) ? 1 : 0;
    int i = w - r * N;

    int o0 = off[(size_t)r * N + i];
    int o1 = (i + 1 < N) ? off[(size_t)r * N + i + 1] : E;
    int d = o1 - o0;
    const int* es = csr + (size_t)r * E;
    const int col = lane * 2;

    float sx = 0.0f, sy = 0.0f;
    int j = o0;
    for (; j + 3 < o1; j += 4) {
        int s0 = es[j], s1 = es[j + 1], s2 = es[j + 2], s3 = es[j + 3];
        float2 a = *(const float2*)(feat + (size_t)s0 * F + col);
        float2 b = *(const float2*)(feat + (size_t)s1 * F + col);
        float2 c = *(const float2*)(feat + (size_t)s2 * F + col);
        float2 e4 = *(const float2*)(feat + (size_t)s3 * F + col);
        sx += (a.x + b.x) + (c.x + e4.x);
        sy += (a.y + b.y) + (c.y + e4.y);
    }
    for (; j < o1; ++j) {
        int s0 = es[j];
        float2 a = *(const float2*)(feat + (size_t)s0 * F + col);
        sx += a.x; sy += a.y;
    }
    float inv = 1.0f / fmaxf((float)d, 1.0f);
    float2 res; res.x = sx * inv; res.y = sy * inv;
    *(float2*)(acc + (size_t)r * N * F + (size_t)i * F + col) = res;
}

// Pre-combine Wself across relations and biases: Wc = Ws[0]+Ws[1], bc = b[0]+b[1].
__global__ void prep_kernel(const float* __restrict__ Ws1, const float* __restrict__ b1,
                            const float* __restrict__ Ws2, const float* __restrict__ b2,
                            float* __restrict__ Wc1, float* __restrict__ bc1,
                            float* __restrict__ Wc2, float* __restrict__ bc2)
{
    int t = blockIdx.x * blockDim.x + threadIdx.x;
    if (t < 16384) Wc1[t] = Ws1[t] + Ws1[16384 + t];
    if (t < 128)   bc1[t] = b1[t] + b1[128 + t];
    if (t < 8192)  Wc2[t] = Ws2[t] + Ws2[8192 + t];
    if (t < 64)    bc2[t] = b2[t] + b2[64 + t];
}

// out[N,BN] = relu?( A0@W0 + A1@W1 + A2@W2 + bias )
// A* all [N,128] row-major (pitch 128), W* [128,BN] row-major.
// Block: BM x BN tile; 256 threads, each 8 rows x 4 cols.
template<int BN>
__global__ __launch_bounds__(256) void
gemm3_kernel(const float* __restrict__ A0, const float* __restrict__ A1,
             const float* __restrict__ A2,
             const float* __restrict__ W0, const float* __restrict__ W1,
             const float* __restrict__ W2,
             const float* __restrict__ bias, float* __restrict__ out,
             int N, int do_relu)
{
    constexpr int TCOLS = BN / 4;        // threads along cols
    constexpr int TROWS = 256 / TCOLS;   // thread groups along rows
    constexpr int BM = TROWS * 8;        // rows per block
    constexpr int BK = 32;
    constexpr int F4_PER_WROW = BN / 4;  // float4s per W row

    __shared__ float As[BK][BM + 4];
    __shared__ float Wsm[BK][BN];

    const int tid = threadIdx.x;
    const int tc = tid % TCOLS;          // col group
    const int tr = tid / TCOLS;          // row group
    const int j0 = tc * 4;
    const int i0 = tr * 8;
    const int rowBase = blockIdx.x * BM;

    float acc[8][4];
#pragma unroll
    for (int r = 0; r < 8; ++r)
#pragma unroll
        for (int c = 0; c < 4; ++c) acc[r][c] = 0.0f;

    const float* Aps[3] = {A0, A1, A2};
    const float* Wps[3] = {W0, W1, W2};

    for (int s = 0; s < 3; ++s) {
        const float* A = Aps[s];
        const float* W = Wps[s];
        for (int k0 = 0; k0 < 128; k0 += BK) {
            // Load A tile [BM][BK] -> As[k][i] (transposed), float4 global loads.
            constexpr int A_F4 = BM * (BK / 4);            // total float4s
#pragma unroll
            for (int p = 0; p < A_F4 / 256; ++p) {
                int q = tid + p * 256;
                int row = q >> 3;                           // BK/4 = 8 f4 per row
                int kq = (q & 7) * 4;
                int rg = rowBase + row;
                if (rg >= N) rg = N - 1;
                float4 v = *(const float4*)(A + (size_t)rg * 128 + k0 + kq);
                As[kq + 0][row] = v.x;
                As[kq + 1][row] = v.y;
                As[kq + 2][row] = v.z;
                As[kq + 3][row] = v.w;
            }
            // Load W tile [BK][BN] -> Wsm, coalesced.
            constexpr int W_F4 = BK * F4_PER_WROW;
#pragma unroll
            for (int p = 0; p < W_F4 / 256; ++p) {
                int q = tid + p * 256;
                int rk = q / F4_PER_WROW;
                int jq = (q % F4_PER_WROW) * 4;
                float4 v = *(const float4*)(W + (size_t)(k0 + rk) * BN + jq);
                *(float4*)&Wsm[rk][jq] = v;
            }
            __syncthreads();

#pragma unroll 8
            for (int k = 0; k < BK; ++k) {
                float4 w = *(const float4*)&Wsm[k][j0];
                const float* ap = &As[k][i0];
                float4 a0 = *(const float4*)(ap);
                float4 a1 = *(const float4*)(ap + 4);
                float av[8] = {a0.x, a0.y, a0.z, a0.w, a1.x, a1.y, a1.z, a1.w};
#pragma unroll
                for (int r = 0; r < 8; ++r) {
                    acc[r][0] = fmaf(av[r], w.x, acc[r][0]);
                    acc[r][1] = fmaf(av[r], w.y, acc[r][1]);
                    acc[r][2] = fmaf(av[r], w.z, acc[r][2]);
                    acc[r][3] = fmaf(av[r], w.w, acc[r][3]);
                }
            }
            __syncthreads();
        }
    }

    float4 bv = *(const float4*)(bias + j0);
#pragma unroll
    for (int r = 0; r < 8; ++r) {
        int row = rowBase + i0 + r;
        if (row >= N) break;
        float4 o;
        o.x = acc[r][0] + bv.x;
        o.y = acc[r][1] + bv.y;
        o.z = acc[r][2] + bv.z;
        o.w = acc[r][3] + bv.w;
        if (do_relu) {
            o.x = fmaxf(o.x, 0.0f); o.y = fmaxf(o.y, 0.0f);
            o.z = fmaxf(o.z, 0.0f); o.w = fmaxf(o.w, 0.0f);
        }
        *(float4*)(out + (size_t)row * BN + j0) = o;
    }
}

__global__ void score_kernel(const float* __restrict__ h, // [N,O]
                             const int* __restrict__ src,
                             const int* __restrict__ dst,
                             float* __restrict__ out, int E, int O)
{
    int e = blockIdx.x * blockDim.x + threadIdx.x;
    if (e >= E) return;
    const float* a = h + (size_t)src[e] * O;
    const float* c = h + (size_t)dst[e] * O;
    float s = 0.0f;
    for (int k = 0; k < O; k += 4) {
        float4 va = *(const float4*)(a + k);
        float4 vb = *(const float4*)(c + k);
        s = fmaf(va.x, vb.x, s);
        s = fmaf(va.y, vb.y, s);
        s = fmaf(va.z, vb.z, s);
        s = fmaf(va.w, vb.w, s);
    }
    out[e] = s;
}

extern "C" void kernel_launch(void* const* d_in, const int* in_sizes, int n_in,
                              void* d_out, int out_size, void* d_ws, size_t ws_size,
                              hipStream_t stream)
{
    const float* x     = (const float*)d_in[0];
    const int*   edges = (const int*)d_in[1];
    const int*   neg   = (const int*)d_in[2];
    const float* Wn1   = (const float*)d_in[3];
    const float* Ws1   = (const float*)d_in[4];
    const float* b1    = (const float*)d_in[5];
    const float* Wn2   = (const float*)d_in[6];
    const float* Ws2   = (const float*)d_in[7];
    const float* b2    = (const float*)d_in[8];
    float* out = (float*)d_out;

    const int Fin = 128, H = 128, O = 64, R = 2;
    const int N  = in_sizes[0] / Fin;        // 50000
    const int E  = in_sizes[1] / (R * 2);    // 800000
    const int En = in_sizes[2] / 2;          // 800000

    float* ws  = (float*)d_ws;
    float* acc = ws;                                   // [R, N, 128]
    float* h1  = acc + (size_t)R * N * 128;            // [N, 128]
    float* h2  = h1 + (size_t)N * 128;                 // [N, 64]
    int*   icnt = (int*)(h2 + (size_t)N * 64);         // [R, N]
    int*   icur = icnt + (size_t)R * N;                // [R, N]
    int*   ioff = icur + (size_t)R * N;                // [R, N]
    int*   icsr = ioff + (size_t)R * N;                // [R, E]
    float* Wc1  = (float*)(icsr + (size_t)R * E);      // [128,128]
    float* bc1  = Wc1 + 128 * 128;                     // [128]
    float* Wc2  = bc1 + 128;                           // [128,64]
    float* bc2  = Wc2 + 128 * 64;                      // [64]

    const int BS = 256;

    // ---- CSR build + weight prep ----
    hipMemsetAsync(icnt, 0, (size_t)2 * R * N * sizeof(int), stream);
    {
        long long total = (long long)R * E;
        long long nb = (total + BS - 1) / BS;
        hist_kernel<<<(dim3)(unsigned)nb, BS, 0, stream>>>(edges, icnt, N, E, R);
    }
    prep_kernel<<<(16384 + BS - 1) / BS, BS, 0, stream>>>(Ws1, b1, Ws2, b2, Wc1, bc1, Wc2, bc2);
    scan_kernel<<<R, 1024, 0, stream>>>(icnt, ioff, N);
    {
        long long total = (long long)R * E;
        long long nb = (total + BS - 1) / BS;
        reorder_kernel<<<(dim3)(unsigned)nb, BS, 0, stream>>>(edges, ioff, icur, icsr, N, E, R);
    }

    const int gm_blocks = (2 * N * 64 + BS - 1) / BS;  // one wave per (r,node)

    // ---- Layer 1 ----
    gather_mean_kernel<<<gm_blocks, BS, 0, stream>>>(x, icsr, ioff, acc, N, Fin, E);
    gemm3_kernel<128><<<(N + 63) / 64, 256, 0, stream>>>(
        x, acc, acc + (size_t)N * 128, Wc1, Wn1, Wn1 + (size_t)128 * 128, bc1, h1, N, 1);

    // ---- Layer 2 ----
    gather_mean_kernel<<<gm_blocks, BS, 0, stream>>>(h1, icsr, ioff, acc, N, H, E);
    gemm3_kernel<64><<<(N + 127) / 128, 256, 0, stream>>>(
        h1, acc, acc + (size_t)N * 128, Wc2, Wn2, Wn2 + (size_t)128 * 64, bc2, h2, N, 0);

    // ---- Scores ----
    score_kernel<<<(E + BS - 1) / BS, BS, 0, stream>>>(h2, edges, edges + E, out, E, O);
    score_kernel<<<(En + BS - 1) / BS, BS, 0, stream>>>(h2, neg, neg + En, out + E, En, O);
}

// Round 4
// 658.888 us; speedup vs baseline: 10.0143x; 1.4936x over previous
//
#include <hip/hip_runtime.h>

// ---------------------------------------------------------------------------
// GraphSAGE 2-layer hetero (R=2) + edge dot-product scorer.
// Round 4: all randomly-gathered feature arrays stored as bf16 to halve
// random-gather L2-miss traffic (validation threshold is bf16-level):
//   xb  = bf16(x)           -> gather_mean L1 + GEMM1 self-term
//   h1b = bf16(relu(h1))    -> gather_mean L2 + GEMM2 self-term (no f32 h1)
//   h2b = bf16(h2)          -> score kernels
// Score kernel: 8 lanes/edge, coalesced 128B row segments, shfl_xor reduce.
// CSR build (by dst, shared by both layers) unchanged.
// ---------------------------------------------------------------------------

__device__ __forceinline__ unsigned short f2bf(float f) {
    unsigned u = __float_as_uint(f);
    unsigned r = u + 0x7FFFu + ((u >> 16) & 1u);
    return (unsigned short)(r >> 16);
}

__global__ void hist_kernel(const int* __restrict__ edges, // [R,2,E]
                            int* __restrict__ cnt,         // [R,N]
                            int N, int E, int R)
{
    long long t = (long long)blockIdx.x * blockDim.x + threadIdx.x;
    long long total = (long long)R * E;
    if (t >= total) return;
    int e = (int)(t % E);
    int r = (int)(t / E);
    int dst = edges[(size_t)r * 2 * E + E + e];
    atomicAdd(&cnt[(size_t)r * N + dst], 1);
}

// One block (1024 threads) per relation: exclusive scan of cnt -> off.
__global__ void scan_kernel(const int* __restrict__ cnt, // [R,N]
                            int* __restrict__ off,       // [R,N]
                            int N)
{
    const int r = blockIdx.x;
    __shared__ int sm[1024];
    __shared__ int carry;
    if (threadIdx.x == 0) carry = 0;
    __syncthreads();
    for (int base = 0; base < N; base += 1024) {
        int i = base + threadIdx.x;
        int v = (i < N) ? cnt[(size_t)r * N + i] : 0;
        sm[threadIdx.x] = v;
        __syncthreads();
        for (int s = 1; s < 1024; s <<= 1) {
            int t = (threadIdx.x >= s) ? sm[threadIdx.x - s] : 0;
            __syncthreads();
            sm[threadIdx.x] += t;
            __syncthreads();
        }
        if (i < N) off[(size_t)r * N + i] = carry + sm[threadIdx.x] - v;
        __syncthreads();
        if (threadIdx.x == 1023) carry += sm[1023];
        __syncthreads();
    }
}

__global__ void reorder_kernel(const int* __restrict__ edges, // [R,2,E]
                               const int* __restrict__ off,   // [R,N]
                               int* __restrict__ cursor,      // [R,N]
                               int* __restrict__ csr,         // [R,E] src ids
                               int N, int E, int R)
{
    long long t = (long long)blockIdx.x * blockDim.x + threadIdx.x;
    long long total = (long long)R * E;
    if (t >= total) return;
    int e = (int)(t % E);
    int r = (int)(t / E);
    int src = edges[(size_t)r * 2 * E + e];
    int dst = edges[(size_t)r * 2 * E + E + e];
    int pos = atomicAdd(&cursor[(size_t)r * N + dst], 1);
    csr[(size_t)r * E + off[(size_t)r * N + dst] + pos] = src;
}

// float32 [n4 float4s] -> bf16
__global__ void cvt_kernel(const float* __restrict__ in,
                           unsigned short* __restrict__ o, int n4)
{
    int t = blockIdx.x * blockDim.x + threadIdx.x;
    if (t >= n4) return;
    float4 v = ((const float4*)in)[t];
    ushort4 r;
    r.x = f2bf(v.x); r.y = f2bf(v.y); r.z = f2bf(v.z); r.w = f2bf(v.w);
    ((ushort4*)o)[t] = r;
}

// One wave per (relation, node): gather-sum bf16 src rows, divide by degree.
// F == 128 bf16: lane handles cols [2*lane, 2*lane+1] packed in one uint.
__global__ __launch_bounds__(256) void
gather_mean_kernel(const unsigned short* __restrict__ featb, // [N,128] bf16
                   const int* __restrict__ csr,              // [R,E]
                   const int* __restrict__ off,              // [R,N]
                   float* __restrict__ acc,                  // [R,N,128] f32
                   int N, int E)
{
    int w = (int)(((long long)blockIdx.x * blockDim.x + threadIdx.x) >> 6);
    int lane = threadIdx.x & 63;
    if (w >= 2 * N) return;
    int r = (w >= N) ? 1 : 0;
    int i = w - r * N;

    int o0 = off[(size_t)r * N + i];
    int o1 = (i + 1 < N) ? off[(size_t)r * N + i + 1] : E;
    int d = o1 - o0;
    const int* es = csr + (size_t)r * E;
    const int col = lane * 2;

    float sx = 0.0f, sy = 0.0f;
    int j = o0;
    for (; j + 3 < o1; j += 4) {
        int s0 = es[j], s1 = es[j + 1], s2 = es[j + 2], s3 = es[j + 3];
        unsigned a = *(const unsigned*)(featb + (size_t)s0 * 128 + col);
        unsigned b = *(const unsigned*)(featb + (size_t)s1 * 128 + col);
        unsigned c = *(const unsigned*)(featb + (size_t)s2 * 128 + col);
        unsigned e4 = *(const unsigned*)(featb + (size_t)s3 * 128 + col);
        sx += __uint_as_float(a << 16) + __uint_as_float(b << 16) +
              __uint_as_float(c << 16) + __uint_as_float(e4 << 16);
        sy += __uint_as_float(a & 0xFFFF0000u) + __uint_as_float(b & 0xFFFF0000u) +
              __uint_as_float(c & 0xFFFF0000u) + __uint_as_float(e4 & 0xFFFF0000u);
    }
    for (; j < o1; ++j) {
        unsigned a = *(const unsigned*)(featb + (size_t)es[j] * 128 + col);
        sx += __uint_as_float(a << 16);
        sy += __uint_as_float(a & 0xFFFF0000u);
    }
    float inv = 1.0f / fmaxf((float)d, 1.0f);
    float2 res; res.x = sx * inv; res.y = sy * inv;
    *(float2*)(acc + (size_t)r * N * 128 + (size_t)i * 128 + col) = res;
}

// Pre-combine Wself across relations and biases.
__global__ void prep_kernel(const float* __restrict__ Ws1, const float* __restrict__ b1,
                            const float* __restrict__ Ws2, const float* __restrict__ b2,
                            float* __restrict__ Wc1, float* __restrict__ bc1,
                            float* __restrict__ Wc2, float* __restrict__ bc2)
{
    int t = blockIdx.x * blockDim.x + threadIdx.x;
    if (t < 16384) Wc1[t] = Ws1[t] + Ws1[16384 + t];
    if (t < 128)   bc1[t] = b1[t] + b1[128 + t];
    if (t < 8192)  Wc2[t] = Ws2[t] + Ws2[8192 + t];
    if (t < 64)    bc2[t] = b2[t] + b2[64 + t];
}

// out = relu?( A0b@W0 + A1@W1 + A2@W2 + bias ), stored as bf16 (+ f32 if outf).
// A0b: [N,128] bf16. A1,A2: [N,128] f32. W*: [128,BN] f32 row-major.
// Block: BM x BN tile; 256 threads, each 8 rows x 4 cols.
template<int BN>
__global__ __launch_bounds__(256) void
gemm3_kernel(const unsigned short* __restrict__ A0b,
             const float* __restrict__ A1, const float* __restrict__ A2,
             const float* __restrict__ W0, const float* __restrict__ W1,
             const float* __restrict__ W2,
             const float* __restrict__ bias,
             unsigned short* __restrict__ outb,
             int N, int do_relu)
{
    constexpr int TCOLS = BN / 4;
    constexpr int TROWS = 256 / TCOLS;
    constexpr int BM = TROWS * 8;
    constexpr int BK = 32;
    constexpr int F4_PER_WROW = BN / 4;

    __shared__ float As[BK][BM + 4];
    __shared__ float Wsm[BK][BN];

    const int tid = threadIdx.x;
    const int tc = tid % TCOLS;
    const int tr = tid / TCOLS;
    const int j0 = tc * 4;
    const int i0 = tr * 8;
    const int rowBase = blockIdx.x * BM;

    float acc[8][4];
#pragma unroll
    for (int r = 0; r < 8; ++r)
#pragma unroll
        for (int c = 0; c < 4; ++c) acc[r][c] = 0.0f;

    const float* Wps[3] = {W0, W1, W2};

    for (int s = 0; s < 3; ++s) {
        const float* A = (s == 1) ? A1 : A2;
        const float* W = Wps[s];
        for (int k0 = 0; k0 < 128; k0 += BK) {
            if (s == 0) {
                // bf16 A tile: BM rows x 32 cols = BM*4 uint4s (8 bf16 each)
                constexpr int A_U4 = BM * 4;
#pragma unroll
                for (int p = 0; p < A_U4 / 256; ++p) {
                    int q = tid + p * 256;
                    int row = q >> 2;
                    int kq = (q & 3) * 8;
                    int rg = rowBase + row;
                    if (rg >= N) rg = N - 1;
                    uint4 v = *(const uint4*)(A0b + (size_t)rg * 128 + k0 + kq);
                    As[kq + 0][row] = __uint_as_float(v.x << 16);
                    As[kq + 1][row] = __uint_as_float(v.x & 0xFFFF0000u);
                    As[kq + 2][row] = __uint_as_float(v.y << 16);
                    As[kq + 3][row] = __uint_as_float(v.y & 0xFFFF0000u);
                    As[kq + 4][row] = __uint_as_float(v.z << 16);
                    As[kq + 5][row] = __uint_as_float(v.z & 0xFFFF0000u);
                    As[kq + 6][row] = __uint_as_float(v.w << 16);
                    As[kq + 7][row] = __uint_as_float(v.w & 0xFFFF0000u);
                }
            } else {
                constexpr int A_F4 = BM * (BK / 4);
#pragma unroll
                for (int p = 0; p < A_F4 / 256; ++p) {
                    int q = tid + p * 256;
                    int row = q >> 3;
                    int kq = (q & 7) * 4;
                    int rg = rowBase + row;
                    if (rg >= N) rg = N - 1;
                    float4 v = *(const float4*)(A + (size_t)rg * 128 + k0 + kq);
                    As[kq + 0][row] = v.x;
                    As[kq + 1][row] = v.y;
                    As[kq + 2][row] = v.z;
                    As[kq + 3][row] = v.w;
                }
            }
            constexpr int W_F4 = BK * F4_PER_WROW;
#pragma unroll
            for (int p = 0; p < W_F4 / 256; ++p) {
                int q = tid + p * 256;
                int rk = q / F4_PER_WROW;
                int jq = (q % F4_PER_WROW) * 4;
                float4 v = *(const float4*)(W + (size_t)(k0 + rk) * BN + jq);
                *(float4*)&Wsm[rk][jq] = v;
            }
            __syncthreads();

#pragma unroll 8
            for (int k = 0; k < BK; ++k) {
                float4 w = *(const float4*)&Wsm[k][j0];
                const float* ap = &As[k][i0];
                float4 a0 = *(const float4*)(ap);
                float4 a1 = *(const float4*)(ap + 4);
                float av[8] = {a0.x, a0.y, a0.z, a0.w, a1.x, a1.y, a1.z, a1.w};
#pragma unroll
                for (int r = 0; r < 8; ++r) {
                    acc[r][0] = fmaf(av[r], w.x, acc[r][0]);
                    acc[r][1] = fmaf(av[r], w.y, acc[r][1]);
                    acc[r][2] = fmaf(av[r], w.z, acc[r][2]);
                    acc[r][3] = fmaf(av[r], w.w, acc[r][3]);
                }
            }
            __syncthreads();
        }
    }

    float4 bv = *(const float4*)(bias + j0);
#pragma unroll
    for (int r = 0; r < 8; ++r) {
        int row = rowBase + i0 + r;
        if (row >= N) break;
        float4 o;
        o.x = acc[r][0] + bv.x;
        o.y = acc[r][1] + bv.y;
        o.z = acc[r][2] + bv.z;
        o.w = acc[r][3] + bv.w;
        if (do_relu) {
            o.x = fmaxf(o.x, 0.0f); o.y = fmaxf(o.y, 0.0f);
            o.z = fmaxf(o.z, 0.0f); o.w = fmaxf(o.w, 0.0f);
        }
        ushort4 ob;
        ob.x = f2bf(o.x); ob.y = f2bf(o.y); ob.z = f2bf(o.z); ob.w = f2bf(o.w);
        *(ushort4*)(outb + (size_t)row * BN + j0) = ob;
    }
}

// 8 lanes per edge; each lane loads one uint4 (8 bf16 = 16B) of src and dst
// rows (coalesced 128B per row), partial dot, shfl_xor reduce over 8 lanes.
__global__ __launch_bounds__(256) void
score_kernel(const unsigned short* __restrict__ h, // [N,64] bf16
             const int* __restrict__ src,
             const int* __restrict__ dst,
             float* __restrict__ out, int E)
{
    int t = blockIdx.x * blockDim.x + threadIdx.x;
    int e = t >> 3;
    int c = t & 7;
    if (e >= E) return;
    int si = src[e], di = dst[e];
    uint4 va = *(const uint4*)(h + (size_t)si * 64 + c * 8);
    uint4 vb = *(const uint4*)(h + (size_t)di * 64 + c * 8);
    float s = 0.0f;
    s = fmaf(__uint_as_float(va.x << 16),         __uint_as_float(vb.x << 16),         s);
    s = fmaf(__uint_as_float(va.x & 0xFFFF0000u), __uint_as_float(vb.x & 0xFFFF0000u), s);
    s = fmaf(__uint_as_float(va.y << 16),         __uint_as_float(vb.y << 16),         s);
    s = fmaf(__uint_as_float(va.y & 0xFFFF0000u), __uint_as_float(vb.y & 0xFFFF0000u), s);
    s = fmaf(__uint_as_float(va.z << 16),         __uint_as_float(vb.z << 16),         s);
    s = fmaf(__uint_as_float(va.z & 0xFFFF0000u), __uint_as_float(vb.z & 0xFFFF0000u), s);
    s = fmaf(__uint_as_float(va.w << 16),         __uint_as_float(vb.w << 16),         s);
    s = fmaf(__uint_as_float(va.w & 0xFFFF0000u), __uint_as_float(vb.w & 0xFFFF0000u), s);
    s += __shfl_xor(s, 1);
    s += __shfl_xor(s, 2);
    s += __shfl_xor(s, 4);
    if (c == 0) out[e] = s;
}

extern "C" void kernel_launch(void* const* d_in, const int* in_sizes, int n_in,
                              void* d_out, int out_size, void* d_ws, size_t ws_size,
                              hipStream_t stream)
{
    const float* x     = (const float*)d_in[0];
    const int*   edges = (const int*)d_in[1];
    const int*   neg   = (const int*)d_in[2];
    const float* Wn1   = (const float*)d_in[3];
    const float* Ws1   = (const float*)d_in[4];
    const float* b1    = (const float*)d_in[5];
    const float* Wn2   = (const float*)d_in[6];
    const float* Ws2   = (const float*)d_in[7];
    const float* b2    = (const float*)d_in[8];
    float* out = (float*)d_out;

    const int Fin = 128, O = 64, R = 2;
    const int N  = in_sizes[0] / Fin;        // 50000
    const int E  = in_sizes[1] / (R * 2);    // 800000
    const int En = in_sizes[2] / 2;          // 800000

    float* ws  = (float*)d_ws;
    float* acc = ws;                                   // [R, N, 128] f32
    float* Wc1 = acc + (size_t)R * N * 128;            // [128,128]
    float* bc1 = Wc1 + 128 * 128;                      // [128]
    float* Wc2 = bc1 + 128;                            // [128,64]
    float* bc2 = Wc2 + 128 * 64;                       // [64]
    int*   icnt = (int*)(bc2 + 64);                    // [R, N]
    int*   icur = icnt + (size_t)R * N;                // [R, N]
    int*   ioff = icur + (size_t)R * N;                // [R, N]
    int*   icsr = ioff + (size_t)R * N;                // [R, E]
    unsigned short* xb  = (unsigned short*)(icsr + (size_t)R * E); // [N,128]
    unsigned short* h1b = xb + (size_t)N * 128;        // [N,128]
    unsigned short* h2b = h1b + (size_t)N * 128;       // [N,64]

    const int BS = 256;

    // ---- CSR build + weight prep + x conversion ----
    hipMemsetAsync(icnt, 0, (size_t)2 * R * N * sizeof(int), stream);
    {
        long long total = (long long)R * E;
        long long nb = (total + BS - 1) / BS;
        hist_kernel<<<(dim3)(unsigned)nb, BS, 0, stream>>>(edges, icnt, N, E, R);
    }
    cvt_kernel<<<(N * 128 / 4 + BS - 1) / BS, BS, 0, stream>>>(x, xb, N * 128 / 4);
    prep_kernel<<<(16384 + BS - 1) / BS, BS, 0, stream>>>(Ws1, b1, Ws2, b2, Wc1, bc1, Wc2, bc2);
    scan_kernel<<<R, 1024, 0, stream>>>(icnt, ioff, N);
    {
        long long total = (long long)R * E;
        long long nb = (total + BS - 1) / BS;
        reorder_kernel<<<(dim3)(unsigned)nb, BS, 0, stream>>>(edges, ioff, icur, icsr, N, E, R);
    }

    const int gm_blocks = (2 * N * 64 + BS - 1) / BS;  // one wave per (r,node)

    // ---- Layer 1 ----
    gather_mean_kernel<<<gm_blocks, BS, 0, stream>>>(xb, icsr, ioff, acc, N, E);
    gemm3_kernel<128><<<(N + 63) / 64, 256, 0, stream>>>(
        xb, acc, acc + (size_t)N * 128, Wc1, Wn1, Wn1 + (size_t)128 * 128, bc1, h1b, N, 1);

    // ---- Layer 2 ----
    gather_mean_kernel<<<gm_blocks, BS, 0, stream>>>(h1b, icsr, ioff, acc, N, E);
    gemm3_kernel<64><<<(N + 127) / 128, 256, 0, stream>>>(
        h1b, acc, acc + (size_t)N * 128, Wc2, Wn2, Wn2 + (size_t)128 * 64, bc2, h2b, N, 0);

    // ---- Scores ----
    {
        long long tp = (long long)E * 8;
        score_kernel<<<(unsigned)((tp + BS - 1) / BS), BS, 0, stream>>>(h2b, edges, edges + E, out, E);
        long long tn = (long long)En * 8;
        score_kernel<<<(unsigned)((tn + BS - 1) / BS), BS, 0, stream>>>(h2b, neg, neg + En, out + E, En);
    }
}